// Round 9
// baseline (185.879 us; speedup 1.0000x reference)
//
#include <hip/hip_runtime.h>
#include <hip/hip_bf16.h>

// Problem shape (fixed by the reference setup_inputs)
constexpr int B = 16, F = 16, H = 256, W = 256;
constexpr int HW = H * W;               // 65536
constexpr int SPATIAL = B * HW;         // 1,048,576 spatial locations
constexpr int NVALS = 65;               // s[16], c[16], dtot[16], sall[16], call
constexpr int PLANE4  = HW / 4;         // 16384 dwords/float4 per (b,f) plane
constexpr int BSTR4   = F * PLANE4;     // 262144 per batch index (float4/dword units)
constexpr int POS4    = SPATIAL / 4;    // 262144 position-dwords (any-mask)

constexpr int NB_A = 1024;              // any-mask pass blocks (256 thr, 1 dword each)
constexpr int NB_B = 2048;              // main pass: 128 chunks x 16 features
constexpr int CHUNKS = NB_B / F;        // 128 blocks per feature
constexpr int ITER = 8;                 // groups per thread in B: 128*256*8 = 262144/feature

// ws layout (dword/float units)
constexpr int WS_ANY = 0;                       // uint any[POS4]            (1 MB)
constexpr int WS_PA  = POS4;                    // float pa[NB_A]            (call partials)
constexpr int WS_PB  = WS_PA + NB_A;            // float pb[64][CHUNKS]
constexpr int WS_VAL = WS_PB + 64 * CHUNKS;     // float vals[NVALS]

// R9: one-shot-wave designs plateaued at 2.6-2.7 TB/s reads regardless of
// MLP forcing (R5-R7) and occupancy (R2-R4); L3-resident replays ran no
// faster, so neither BW nor latency explains it. This round adopts the only
// structure measured at ~6.3 TB/s on this chip (grid-stride streaming loop,
// tiny register state, independent iterations): feature-per-block streams,
// with the cross-feature any-mask precomputed by kernel A.

// ---- Kernel A: any-mask + call partials. 16 strided dword loads -> OR. ----
__global__ __launch_bounds__(256) void heat_any(
        const unsigned int* __restrict__ msk, unsigned int* __restrict__ any,
        float* __restrict__ pa) {
    const int p4 = blockIdx.x * 256 + threadIdx.x;   // [0, POS4)
    const int b   = p4 >> 14;                        // p4 / PLANE4
    const int hw4 = p4 & (PLANE4 - 1);
    const int base = b * BSTR4 + hw4;
    unsigned int a = 0;
    #pragma unroll
    for (int f = 0; f < F; f++) a |= msk[base + f * PLANE4];
    any[p4] = a;                                     // bytes are 0/1 (OR of 0/1)
    float cnt = (float)((a & 1u) + ((a >> 8) & 1u) + ((a >> 16) & 1u) + (a >> 24));
    #pragma unroll
    for (int o = 32; o > 0; o >>= 1) cnt += __shfl_down(cnt, o, 64);
    __shared__ float red[4];
    if ((threadIdx.x & 63) == 0) red[threadIdx.x >> 6] = cnt;
    __syncthreads();
    if (threadIdx.x == 0) pa[blockIdx.x] = (red[0] + red[1]) + (red[2] + red[3]);
}

// ---- Kernel B: one feature per block; memcpy-shaped streaming loop. ----
__global__ __launch_bounds__(256) void heat_stream(
        const float4* __restrict__ inp, const float4* __restrict__ tgt,
        const unsigned int* __restrict__ msk, const unsigned int* __restrict__ any,
        float* __restrict__ pb) {
    const int f     = blockIdx.x & 15;
    const int chunk = blockIdx.x >> 4;               // 0..127
    const int t     = threadIdx.x;
    const int g0    = chunk * (256 * ITER) + t;      // first group for this thread

    float s = 0.f, c = 0.f, dt = 0.f, sa = 0.f;
    #pragma unroll 4
    for (int i = 0; i < ITER; i++) {
        const int g   = g0 + i * 256;                // group in [0, 262144) for feature f
        const int b   = g >> 14;
        const int hw4 = g & (PLANE4 - 1);
        const int di  = b * BSTR4 + f * PLANE4 + hw4;   // data/mask dword-or-float4 idx
        const int ai  = b * PLANE4 + hw4;               // any-mask dword idx
        const float4 av = inp[di];
        const float4 tv = tgt[di];
        const unsigned int mm = msk[di];
        const unsigned int aa = any[ai];
        const float d0 = fabsf(av.x - tv.x);
        const float d1 = fabsf(av.y - tv.y);
        const float d2 = fabsf(av.z - tv.z);
        const float d3 = fabsf(av.w - tv.w);
        const float m0 = (float)( mm        & 0xFFu);
        const float m1 = (float)((mm >> 8)  & 0xFFu);
        const float m2 = (float)((mm >> 16) & 0xFFu);
        const float m3 = (float)( mm >> 24);
        const float a0 = (float)( aa        & 0xFFu);
        const float a1 = (float)((aa >> 8)  & 0xFFu);
        const float a2 = (float)((aa >> 16) & 0xFFu);
        const float a3 = (float)( aa >> 24);
        dt += (d0 + d1) + (d2 + d3);
        s  += m0 * d0 + m1 * d1 + m2 * d2 + m3 * d3;
        c  += (m0 + m1) + (m2 + m3);
        sa += a0 * d0 + a1 * d1 + a2 * d2 + a3 * d3;
    }

    // Block reduce 4 scalars (4 waves), write pb[(vt*16+f)*CHUNKS + chunk].
    #pragma unroll
    for (int o = 32; o > 0; o >>= 1) {
        s  += __shfl_down(s,  o, 64);
        c  += __shfl_down(c,  o, 64);
        dt += __shfl_down(dt, o, 64);
        sa += __shfl_down(sa, o, 64);
    }
    __shared__ float red[4][4];                      // [wave][vt]
    const int wave = t >> 6;
    if ((t & 63) == 0) {
        red[wave][0] = s; red[wave][1] = c; red[wave][2] = dt; red[wave][3] = sa;
    }
    __syncthreads();
    if (t < 4) {                                     // t = vt
        const float v = red[0][t] + red[1][t] + red[2][t] + red[3][t];
        pb[(t * 16 + f) * CHUNKS + chunk] = v;
    }
}

// ---- Stage 2: 65 blocks -> vals[65]. v<64 sums pb, v=64 sums pa. ----
__global__ __launch_bounds__(256) void heat_reduce(
        const float* __restrict__ pa, const float* __restrict__ pb,
        float* __restrict__ vals) {
    const int v = blockIdx.x;
    const int t = threadIdx.x;
    float x = 0.f;
    if (v < 64) {
        if (t < CHUNKS) x = pb[v * CHUNKS + t];
    } else {
        #pragma unroll
        for (int k = 0; k < NB_A / 256; k++) x += pa[t + k * 256];
    }
    #pragma unroll
    for (int o = 32; o > 0; o >>= 1) x += __shfl_down(x, o, 64);
    __shared__ float red[4];
    if ((t & 63) == 0) red[t >> 6] = x;
    __syncthreads();
    if (t == 0) vals[v] = (red[0] + red[1]) + (red[2] + red[3]);
}

// ---- Stage 3: combine 65 sums into the scalar loss. ----
__global__ __launch_bounds__(128) void heat_combine(
        const float* __restrict__ vals_in, float* __restrict__ out) {
    __shared__ float vals[NVALS];
    const int t = threadIdx.x;
    if (t < NVALS) vals[t] = vals_in[t];
    __syncthreads();
    if (t == 0) {
        const float Nf = (float)SPATIAL;
        const float call = vals[64];
        float lf = 0.f, lbg = 0.f, lall = 0.f;
        #pragma unroll
        for (int f = 0; f < F; f++) {
            const float sf = vals[f], cf = vals[16 + f];
            const float dtv = vals[32 + f], sav = vals[48 + f];
            lf += (cf > 0.f) ? sf / cf : 0.f;
            const float sbg = dtv - sf, cbg = Nf - cf;
            lbg += (cbg > 0.f) ? sbg / cbg : 0.f;
            lall += (call > 0.f) ? sav / call : 0.f;
        }
        out[0] = (lf / 16.f + lbg / 16.f + lall / 16.f) / 3.f;
    }
}

extern "C" void kernel_launch(void* const* d_in, const int* in_sizes, int n_in,
                              void* d_out, int out_size, void* d_ws, size_t ws_size,
                              hipStream_t stream) {
    const float4*       inp = (const float4*)d_in[0];
    const float4*       tgt = (const float4*)d_in[1];
    const unsigned int* msk = (const unsigned int*)d_in[2];   // jnp.bool_ bytes
    float* out = (float*)d_out;
    unsigned int* ws_u = (unsigned int*)d_ws;
    float*        ws_f = (float*)d_ws;
    unsigned int* any  = ws_u + WS_ANY;     // [POS4]
    float*        pa   = ws_f + WS_PA;      // [NB_A]
    float*        pb   = ws_f + WS_PB;      // [64][CHUNKS]
    float*        vals = ws_f + WS_VAL;     // [NVALS]

    heat_any<<<NB_A, 256, 0, stream>>>(msk, any, pa);
    heat_stream<<<NB_B, 256, 0, stream>>>(inp, tgt, msk, any, pb);
    heat_reduce<<<NVALS, 256, 0, stream>>>(pa, pb, vals);
    heat_combine<<<1, 128, 0, stream>>>(vals, out);
}